// Round 2
// baseline (261.521 us; speedup 1.0000x reference)
//
#include <hip/hip_runtime.h>
#include <hip/hip_bf16.h>
#include <math.h>

#define THREADS 256
typedef unsigned short ushortT;
typedef __attribute__((ext_vector_type(8))) short bf16x8;   // 8 bf16 = 4 VGPRs
typedef __attribute__((ext_vector_type(4))) float f32x4;

__device__ __forceinline__ void async16(const ushortT* g, ushortT* l) {
  __builtin_amdgcn_global_load_lds(
      (const __attribute__((address_space(1))) unsigned int*)g,
      (__attribute__((address_space(3))) unsigned int*)l, 16, 0, 0);
}

__device__ __forceinline__ ushortT f2bf(float f) {
  __hip_bfloat16 h = __float2bfloat16(f);
  return *reinterpret_cast<ushortT*>(&h);
}

// ---------------------------------------------------------------------------
// Kernel A: fused L2-norm + bf16 convert. One block per row (256 thr x float4).
// ---------------------------------------------------------------------------
__global__ __launch_bounds__(THREADS) void k_prep(const float* __restrict__ x,
                                                  ushortT* __restrict__ xn, int D) {
  __shared__ float red[4];
  const int row = blockIdx.x;
  const int tid = threadIdx.x;
  const int gid = row * (D / 4) + tid;
  const float4 v = reinterpret_cast<const float4*>(x)[gid];
  float s = v.x * v.x + v.y * v.y + v.z * v.z + v.w * v.w;
  #pragma unroll
  for (int off = 32; off; off >>= 1) s += __shfl_xor(s, off);
  if ((tid & 63) == 0) red[tid >> 6] = s;
  __syncthreads();
  const float tot = red[0] + red[1] + red[2] + red[3];
  const float rn = 1.0f / fmaxf(sqrtf(tot), 1e-12f);
  ushort4 o;
  o.x = f2bf(v.x * rn); o.y = f2bf(v.y * rn);
  o.z = f2bf(v.z * rn); o.w = f2bf(v.w * rn);
  reinterpret_cast<ushort4*>(xn)[gid] = o;
}

// ---------------------------------------------------------------------------
// Kernel B: triangular 128x128 bf16 MFMA tiles + dual-orientation circle-loss
// epilogue. Block b -> (bi <= bj). Staging in fragment-read order (0 bank
// conflicts). Occupancy round: __launch_bounds__(256,4) forces the <=128
// unified-reg bucket (4 waves/SIMD -> 4 blocks/CU vs previous 2):
//   - orientation-2 sel[16] removed (recompute lp after the max reduce,
//     sentinel -2e30 inline -> algebraically identical contributions)
//   - bfr[4] split into 2x2 (K-loop frag live set 32 -> 24 regs)
//   - staging addresses: uniform 64-bit base + 32-bit lane voffset
// partial[(row*NB + cb)*2 + half] = {mp, sp, 0, sn}
// ---------------------------------------------------------------------------
__global__ __launch_bounds__(THREADS, 4) void k_main_mfma(const ushortT* __restrict__ xn,
                                                          const int* __restrict__ tgt,
                                                          float4* __restrict__ partial,
                                                          int D, int nb) {
  __shared__ ushortT Asm[128 * 32];  // 8 KB
  __shared__ ushortT Bsm[128 * 32];  // 8 KB

  const int tid = threadIdx.x;
  const int lane = tid & 63;
  const int w = tid >> 6;

  // --- triangular decode: b -> (bi, bj), bi <= bj
  const int b = blockIdx.x;
  int bi = (int)((2.f * nb + 1.f -
                  sqrtf((2.f * nb + 1.f) * (2.f * nb + 1.f) - 8.f * (float)b)) * 0.5f);
  while ((bi + 1) * (2 * nb - bi) / 2 <= b) ++bi;
  while (bi * (2 * nb - bi + 1) / 2 > b) --bi;
  const int bj = bi + (b - bi * (2 * nb - bi + 1) / 2);
  const bool isdiag = (bi == bj);

  const int i0 = bi * 128, j0 = bj * 128;
  const int wr = (w >> 1) * 64, wc = (w & 1) * 64;

  // --- staging: lane fetches (row = lane&15, chunk = lane>>4) of its group
  const int sr = lane & 15, sc = lane >> 4;
  const ushortT* baseA = xn + (size_t)i0 * D;   // wave-uniform 64-bit base
  const ushortT* baseB = xn + (size_t)j0 * D;
  const int offA = (w * 16 + sr) * D + sc * 8;  // 32-bit lane offset
  const int hstep = 64 * D;
  ushortT* lA0 = &Asm[w * 512];
  ushortT* lA1 = &Asm[(w + 4) * 512];
  ushortT* lB0 = &Bsm[w * 512];
  ushortT* lB1 = &Bsm[(w + 4) * 512];

  const ushortT* Bbase = isdiag ? Asm : Bsm;
  const int aoff = ((w >> 1) * 4) * 512 + lane * 8;   // ushort index
  const int boff = ((w & 1) * 4) * 512 + lane * 8;

  f32x4 acc[4][4];
  #pragma unroll
  for (int mt = 0; mt < 4; ++mt)
    #pragma unroll
    for (int nt = 0; nt < 4; ++nt)
      acc[mt][nt] = (f32x4){0.f, 0.f, 0.f, 0.f};

  const int kiters = D / 32;
  for (int kk = 0; kk < kiters; ++kk) {
    const int ko = kk * 32;
    async16(baseA + offA + ko, lA0);
    async16(baseA + offA + hstep + ko, lA1);
    if (!isdiag) {
      async16(baseB + offA + ko, lB0);
      async16(baseB + offA + hstep + ko, lB1);
    }
    __syncthreads();
    bf16x8 afr[4];
    #pragma unroll
    for (int mt = 0; mt < 4; ++mt)
      afr[mt] = *reinterpret_cast<const bf16x8*>(&Asm[aoff + mt * 512]);
    {
      bf16x8 b0 = *reinterpret_cast<const bf16x8*>(&Bbase[boff]);
      bf16x8 b1 = *reinterpret_cast<const bf16x8*>(&Bbase[boff + 512]);
      #pragma unroll
      for (int mt = 0; mt < 4; ++mt)
        acc[mt][0] = __builtin_amdgcn_mfma_f32_16x16x32_bf16(afr[mt], b0, acc[mt][0], 0, 0, 0);
      #pragma unroll
      for (int mt = 0; mt < 4; ++mt)
        acc[mt][1] = __builtin_amdgcn_mfma_f32_16x16x32_bf16(afr[mt], b1, acc[mt][1], 0, 0, 0);
      b0 = *reinterpret_cast<const bf16x8*>(&Bbase[boff + 2 * 512]);
      b1 = *reinterpret_cast<const bf16x8*>(&Bbase[boff + 3 * 512]);
      #pragma unroll
      for (int mt = 0; mt < 4; ++mt)
        acc[mt][2] = __builtin_amdgcn_mfma_f32_16x16x32_bf16(afr[mt], b0, acc[mt][2], 0, 0, 0);
      #pragma unroll
      for (int mt = 0; mt < 4; ++mt)
        acc[mt][3] = __builtin_amdgcn_mfma_f32_16x16x32_bf16(afr[mt], b1, acc[mt][3], 0, 0, 0);
    }
    __syncthreads();
  }

  // --- epilogue. C/D layout: col = lane&15, row = (lane>>4)*4 + reg
  const int q = lane >> 4, c = lane & 15;
  int tj[4];
  #pragma unroll
  for (int nt = 0; nt < 4; ++nt) tj[nt] = tgt[j0 + wc + nt * 16 + c];
  int tir[16];
  #pragma unroll
  for (int mt = 0; mt < 4; ++mt) {
    const int4 t4 = *reinterpret_cast<const int4*>(tgt + i0 + wr + mt * 16 + q * 4);
    tir[mt * 4 + 0] = t4.x; tir[mt * 4 + 1] = t4.y;
    tir[mt * 4 + 2] = t4.z; tir[mt * 4 + 3] = t4.w;
  }

  // orientation 1: rows of bi block, cols of bj block
  #pragma unroll
  for (int mt = 0; mt < 4; ++mt) {
    #pragma unroll
    for (int reg = 0; reg < 4; ++reg) {
      const int i = i0 + wr + mt * 16 + q * 4 + reg;
      const int ti = tir[mt * 4 + reg];
      float m = -1e30f, sn = 0.f;
      float sel[4];
      #pragma unroll
      for (int nt = 0; nt < 4; ++nt) {
        const float s = acc[mt][nt][reg];
        const int j = j0 + wc + nt * 16 + c;
        const bool same = (tj[nt] == ti);
        const bool vpos = same && (j != i);
        const float lp = (fminf(s, 1.25f) - 1.25f) * fmaf(s, 64.f, -48.f);
        const float sv = vpos ? lp : -2e30f;
        sel[nt] = sv;
        m = fmaxf(m, sv);
        const float ln = (fmaxf(s, -0.25f) + 0.25f) * fmaf(s, 64.f, -16.f);
        const float en = __expf(ln);
        sn += same ? 0.f : en;
      }
      #pragma unroll
      for (int off = 1; off < 16; off <<= 1) m = fmaxf(m, __shfl_xor(m, off));
      float sp = 0.f;
      #pragma unroll
      for (int nt = 0; nt < 4; ++nt) sp += __expf(sel[nt] - m);
      #pragma unroll
      for (int off = 1; off < 16; off <<= 1) {
        sp += __shfl_xor(sp, off);
        sn += __shfl_xor(sn, off);
      }
      if (c == 0) {
        float4 o; o.x = m; o.y = sp; o.z = 0.f; o.w = sn;
        partial[((size_t)i * nb + bj) * 2 + (w & 1)] = o;
      }
    }
  }

  // orientation 2: rows of bj block, cols of bi block (off-diagonal only).
  // Two-pass, register-lean: pass 1 finds max (sentinel inline) + neg sum,
  // pass 2 recomputes lp and accumulates exp(lp - m). Identical math to the
  // previous sel[16] version: exp(-2e30 - m) == 0 for any reachable m.
  if (!isdiag) {
    #pragma unroll
    for (int nt = 0; nt < 4; ++nt) {
      const int jt = tj[nt];
      const int jrow = j0 + wc + nt * 16 + c;
      float m = -1e30f, sn = 0.f;
      #pragma unroll
      for (int mt = 0; mt < 4; ++mt) {
        #pragma unroll
        for (int reg = 0; reg < 4; ++reg) {
          const float s = acc[mt][nt][reg];
          const bool same = (tir[mt * 4 + reg] == jt);  // j != i guaranteed off-diag
          const float lp = (fminf(s, 1.25f) - 1.25f) * fmaf(s, 64.f, -48.f);
          m = fmaxf(m, same ? lp : -2e30f);
          const float ln = (fmaxf(s, -0.25f) + 0.25f) * fmaf(s, 64.f, -16.f);
          const float en = __expf(ln);
          sn += same ? 0.f : en;
        }
      }
      m = fmaxf(m, __shfl_xor(m, 16));
      m = fmaxf(m, __shfl_xor(m, 32));
      float sp = 0.f;
      #pragma unroll
      for (int mt = 0; mt < 4; ++mt) {
        #pragma unroll
        for (int reg = 0; reg < 4; ++reg) {
          const float s = acc[mt][nt][reg];
          const bool same = (tir[mt * 4 + reg] == jt);
          const float lp = (fminf(s, 1.25f) - 1.25f) * fmaf(s, 64.f, -48.f);
          sp += __expf((same ? lp : -2e30f) - m);
        }
      }
      sp += __shfl_xor(sp, 16); sp += __shfl_xor(sp, 32);
      sn += __shfl_xor(sn, 16); sn += __shfl_xor(sn, 32);
      if (lane < 16) {
        float4 o; o.x = m; o.y = sp; o.z = 0.f; o.w = sn;
        partial[((size_t)jrow * nb + bi) * 2 + (w >> 1)] = o;
      }
    }
  }
}

// ---------------------------------------------------------------------------
// Kernel C: fold 128 partials per row -> row loss. One wave per row.
// ---------------------------------------------------------------------------
__global__ __launch_bounds__(THREADS) void k_reduce(const float4* __restrict__ partial,
                                                    float* __restrict__ row_loss) {
  const int lane = threadIdx.x & 63;
  const int row = blockIdx.x * 4 + (threadIdx.x >> 6);
  const float4 a = partial[(size_t)row * 128 + lane];
  const float4 b = partial[(size_t)row * 128 + 64 + lane];
  float mp = fmaxf(a.x, b.x);
  float sp = a.y * __expf(a.x - mp) + b.y * __expf(b.x - mp);
  float sn = a.w + b.w;
  #pragma unroll
  for (int off = 1; off < 64; off <<= 1) {
    const float m2 = __shfl_xor(mp, off), s2 = __shfl_xor(sp, off);
    const float nm = fmaxf(mp, m2);
    sp = sp * __expf(mp - nm) + s2 * __expf(m2 - nm);
    mp = nm;
    sn += __shfl_xor(sn, off);
  }
  if (lane == 0) {
    float loss = -1.0f;
    if (sp > 0.f && sn > 0.f) {
      const float z = mp + logf(sp) + logf(sn);
      loss = (z > 0.f) ? (z + log1pf(__expf(-z))) : log1pf(__expf(z));
    }
    row_loss[row] = loss;
  }
}

// ---------------------------------------------------------------------------
// Kernel D: masked mean over rows. One block.
// ---------------------------------------------------------------------------
__global__ __launch_bounds__(THREADS) void k_final(const float* __restrict__ row_loss,
                                                   float* __restrict__ out, int B) {
  __shared__ float ssum[4];
  __shared__ float scnt[4];
  const int tid = threadIdx.x;
  float sum = 0.f, cnt = 0.f;
  for (int i = tid; i < B; i += THREADS) {
    const float l = row_loss[i];
    if (l >= 0.f) { sum += l; cnt += 1.f; }
  }
  #pragma unroll
  for (int off = 32; off; off >>= 1) {
    sum += __shfl_xor(sum, off);
    cnt += __shfl_xor(cnt, off);
  }
  if ((tid & 63) == 0) { ssum[tid >> 6] = sum; scnt[tid >> 6] = cnt; }
  __syncthreads();
  if (tid == 0) {
    float ts = 0.f, tc = 0.f;
    #pragma unroll
    for (int w = 0; w < 4; ++w) { ts += ssum[w]; tc += scnt[w]; }
    out[0] = ts / fmaxf(tc, 1.f);
  }
}

// ---------------------------------------------------------------------------
extern "C" void kernel_launch(void* const* d_in, const int* in_sizes, int n_in,
                              void* d_out, int out_size, void* d_ws, size_t ws_size,
                              hipStream_t stream) {
  const float* x = (const float*)d_in[0];
  const int* tgt = (const int*)d_in[1];
  float* out = (float*)d_out;
  const int B = in_sizes[1];
  const int D = in_sizes[0] / B;
  const int nb = B / 128;

  ushortT* xn = (ushortT*)d_ws;                                   // B*D bf16 (16 MB)
  float4* partial = (float4*)((char*)d_ws + (size_t)B * D * 2);   // B*2*nb float4 (16 MB)
  float* row_loss = (float*)((char*)d_ws + (size_t)B * D * 2 + (size_t)B * 2 * nb * 16);

  k_prep<<<B, THREADS, 0, stream>>>(x, xn, D);
  k_main_mfma<<<nb * (nb + 1) / 2, THREADS, 0, stream>>>(xn, tgt, partial, D, nb);
  k_reduce<<<B / 4, THREADS, 0, stream>>>(partial, row_loss);
  k_final<<<1, THREADS, 0, stream>>>(row_loss, out, B);
}

// Round 3
// 251.757 us; speedup vs baseline: 1.0388x; 1.0388x over previous
//
#include <hip/hip_runtime.h>
#include <hip/hip_bf16.h>
#include <math.h>

#define THREADS 256
typedef unsigned short ushortT;
typedef __attribute__((ext_vector_type(8))) short bf16x8;   // 8 bf16 = 4 VGPRs
typedef __attribute__((ext_vector_type(4))) float f32x4;

__device__ __forceinline__ void async16(const ushortT* g, ushortT* l) {
  __builtin_amdgcn_global_load_lds(
      (const __attribute__((address_space(1))) unsigned int*)g,
      (__attribute__((address_space(3))) unsigned int*)l, 16, 0, 0);
}

__device__ __forceinline__ ushortT f2bf(float f) {
  __hip_bfloat16 h = __float2bfloat16(f);
  return *reinterpret_cast<ushortT*>(&h);
}

// ---------------------------------------------------------------------------
// Kernel A: fused L2-norm + bf16 convert. One block per row (256 thr x float4).
// ---------------------------------------------------------------------------
__global__ __launch_bounds__(THREADS) void k_prep(const float* __restrict__ x,
                                                  ushortT* __restrict__ xn, int D) {
  __shared__ float red[4];
  const int row = blockIdx.x;
  const int tid = threadIdx.x;
  const int gid = row * (D / 4) + tid;
  const float4 v = reinterpret_cast<const float4*>(x)[gid];
  float s = v.x * v.x + v.y * v.y + v.z * v.z + v.w * v.w;
  #pragma unroll
  for (int off = 32; off; off >>= 1) s += __shfl_xor(s, off);
  if ((tid & 63) == 0) red[tid >> 6] = s;
  __syncthreads();
  const float tot = red[0] + red[1] + red[2] + red[3];
  const float rn = 1.0f / fmaxf(sqrtf(tot), 1e-12f);
  ushort4 o;
  o.x = f2bf(v.x * rn); o.y = f2bf(v.y * rn);
  o.z = f2bf(v.z * rn); o.w = f2bf(v.w * rn);
  reinterpret_cast<ushort4*>(xn)[gid] = o;
}

// ---------------------------------------------------------------------------
// Kernel B: triangular 128x128 bf16 MFMA tiles + dual-orientation circle-loss
// epilogue. Block b -> (bi <= bj).
//
// Round-2 analysis: grid = 528 blocks / 256 CU = 2.06 blocks/CU -> occupancy
// is GRID-limited, not register-limited (round-1's (256,4) only bought 54 MB
// of scratch spills: WRITE_SIZE 16->70 MB, dur 173->188 us). The real cost is
// exposed global->LDS latency: each K-iter drained vmcnt(0) before compute.
//
// This version: T3-minimum 2-phase pipeline. Double-buffered LDS (32 KB);
// iteration kk issues global_load_lds for tile kk+1 into buf[cur^1], then
// ds_reads + MFMAs tile kk from buf[cur], then ONE __syncthreads (compiler
// emits vmcnt(0)+lgkmcnt(0)+s_barrier) -> prefetch latency hides under the
// compute phase; barrier count halves. Buffer hazard: buf[cur^1] was last
// read before the previous iteration's barrier, so overwrite is safe.
// Registers back to (256,2): no spills.
// partial[(row*NB + cb)*2 + half] = {mp, sp, 0, sn}
// ---------------------------------------------------------------------------
__global__ __launch_bounds__(THREADS, 2) void k_main_mfma(const ushortT* __restrict__ xn,
                                                          const int* __restrict__ tgt,
                                                          float4* __restrict__ partial,
                                                          int D, int nb) {
  __shared__ ushortT Asm[2][128 * 32];  // 2 x 8 KB
  __shared__ ushortT Bsm[2][128 * 32];  // 2 x 8 KB

  const int tid = threadIdx.x;
  const int lane = tid & 63;
  const int w = tid >> 6;

  // --- triangular decode: b -> (bi, bj), bi <= bj
  const int b = blockIdx.x;
  int bi = (int)((2.f * nb + 1.f -
                  sqrtf((2.f * nb + 1.f) * (2.f * nb + 1.f) - 8.f * (float)b)) * 0.5f);
  while ((bi + 1) * (2 * nb - bi) / 2 <= b) ++bi;
  while (bi * (2 * nb - bi + 1) / 2 > b) --bi;
  const int bj = bi + (b - bi * (2 * nb - bi + 1) / 2);
  const bool isdiag = (bi == bj);

  const int i0 = bi * 128, j0 = bj * 128;
  const int wr = (w >> 1) * 64, wc = (w & 1) * 64;

  // --- staging: lane fetches (row = lane&15, chunk = lane>>4) of its group
  const int sr = lane & 15, sc = lane >> 4;
  const ushortT* baseA = xn + (size_t)i0 * D;   // wave-uniform 64-bit base
  const ushortT* baseB = xn + (size_t)j0 * D;
  const int offA = (w * 16 + sr) * D + sc * 8;  // 32-bit lane offset
  const int hstep = 64 * D;

  const int aoff = ((w >> 1) * 4) * 512 + lane * 8;   // ushort index
  const int boff = ((w & 1) * 4) * 512 + lane * 8;

  f32x4 acc[4][4];
  #pragma unroll
  for (int mt = 0; mt < 4; ++mt)
    #pragma unroll
    for (int nt = 0; nt < 4; ++nt)
      acc[mt][nt] = (f32x4){0.f, 0.f, 0.f, 0.f};

  const int kiters = D / 32;

  // prologue: stage tile 0 into buffer 0
  {
    async16(baseA + offA, &Asm[0][w * 512]);
    async16(baseA + offA + hstep, &Asm[0][(w + 4) * 512]);
    if (!isdiag) {
      async16(baseB + offA, &Bsm[0][w * 512]);
      async16(baseB + offA + hstep, &Bsm[0][(w + 4) * 512]);
    }
  }
  __syncthreads();

  int cur = 0;
  for (int kk = 0; kk < kiters; ++kk) {
    // issue next tile's loads into the other buffer (hazard-free: that buffer
    // was last read before the previous iteration's barrier)
    if (kk + 1 < kiters) {
      const int ko = (kk + 1) * 32;
      const int nxt = cur ^ 1;
      async16(baseA + offA + ko, &Asm[nxt][w * 512]);
      async16(baseA + offA + hstep + ko, &Asm[nxt][(w + 4) * 512]);
      if (!isdiag) {
        async16(baseB + offA + ko, &Bsm[nxt][w * 512]);
        async16(baseB + offA + hstep + ko, &Bsm[nxt][(w + 4) * 512]);
      }
    }

    const ushortT* Ab = Asm[cur];
    const ushortT* Bb = isdiag ? Asm[cur] : Bsm[cur];
    bf16x8 afr[4];
    #pragma unroll
    for (int mt = 0; mt < 4; ++mt)
      afr[mt] = *reinterpret_cast<const bf16x8*>(&Ab[aoff + mt * 512]);
    {
      bf16x8 b0 = *reinterpret_cast<const bf16x8*>(&Bb[boff]);
      bf16x8 b1 = *reinterpret_cast<const bf16x8*>(&Bb[boff + 512]);
      #pragma unroll
      for (int mt = 0; mt < 4; ++mt)
        acc[mt][0] = __builtin_amdgcn_mfma_f32_16x16x32_bf16(afr[mt], b0, acc[mt][0], 0, 0, 0);
      #pragma unroll
      for (int mt = 0; mt < 4; ++mt)
        acc[mt][1] = __builtin_amdgcn_mfma_f32_16x16x32_bf16(afr[mt], b1, acc[mt][1], 0, 0, 0);
      b0 = *reinterpret_cast<const bf16x8*>(&Bb[boff + 2 * 512]);
      b1 = *reinterpret_cast<const bf16x8*>(&Bb[boff + 3 * 512]);
      #pragma unroll
      for (int mt = 0; mt < 4; ++mt)
        acc[mt][2] = __builtin_amdgcn_mfma_f32_16x16x32_bf16(afr[mt], b0, acc[mt][2], 0, 0, 0);
      #pragma unroll
      for (int mt = 0; mt < 4; ++mt)
        acc[mt][3] = __builtin_amdgcn_mfma_f32_16x16x32_bf16(afr[mt], b1, acc[mt][3], 0, 0, 0);
    }
    __syncthreads();   // drains vmcnt(0)+lgkmcnt(0): next buffer ready
    cur ^= 1;
  }

  // --- epilogue. C/D layout: col = lane&15, row = (lane>>4)*4 + reg
  const int q = lane >> 4, c = lane & 15;
  int tj[4];
  #pragma unroll
  for (int nt = 0; nt < 4; ++nt) tj[nt] = tgt[j0 + wc + nt * 16 + c];
  int tir[16];
  #pragma unroll
  for (int mt = 0; mt < 4; ++mt) {
    const int4 t4 = *reinterpret_cast<const int4*>(tgt + i0 + wr + mt * 16 + q * 4);
    tir[mt * 4 + 0] = t4.x; tir[mt * 4 + 1] = t4.y;
    tir[mt * 4 + 2] = t4.z; tir[mt * 4 + 3] = t4.w;
  }

  // orientation 1: rows of bi block, cols of bj block
  #pragma unroll
  for (int mt = 0; mt < 4; ++mt) {
    #pragma unroll
    for (int reg = 0; reg < 4; ++reg) {
      const int i = i0 + wr + mt * 16 + q * 4 + reg;
      const int ti = tir[mt * 4 + reg];
      float m = -1e30f, sn = 0.f;
      float sel[4];
      #pragma unroll
      for (int nt = 0; nt < 4; ++nt) {
        const float s = acc[mt][nt][reg];
        const int j = j0 + wc + nt * 16 + c;
        const bool same = (tj[nt] == ti);
        const bool vpos = same && (j != i);
        const float lp = (fminf(s, 1.25f) - 1.25f) * fmaf(s, 64.f, -48.f);
        const float sv = vpos ? lp : -2e30f;
        sel[nt] = sv;
        m = fmaxf(m, sv);
        const float ln = (fmaxf(s, -0.25f) + 0.25f) * fmaf(s, 64.f, -16.f);
        const float en = __expf(ln);
        sn += same ? 0.f : en;
      }
      #pragma unroll
      for (int off = 1; off < 16; off <<= 1) m = fmaxf(m, __shfl_xor(m, off));
      float sp = 0.f;
      #pragma unroll
      for (int nt = 0; nt < 4; ++nt) sp += __expf(sel[nt] - m);
      #pragma unroll
      for (int off = 1; off < 16; off <<= 1) {
        sp += __shfl_xor(sp, off);
        sn += __shfl_xor(sn, off);
      }
      if (c == 0) {
        float4 o; o.x = m; o.y = sp; o.z = 0.f; o.w = sn;
        partial[((size_t)i * nb + bj) * 2 + (w & 1)] = o;
      }
    }
  }

  // orientation 2: rows of bj block, cols of bi block (off-diagonal only).
  // Two-pass, register-lean: pass 1 finds max (sentinel inline) + neg sum,
  // pass 2 recomputes lp and accumulates exp(lp - m).
  if (!isdiag) {
    #pragma unroll
    for (int nt = 0; nt < 4; ++nt) {
      const int jt = tj[nt];
      const int jrow = j0 + wc + nt * 16 + c;
      float m = -1e30f, sn = 0.f;
      #pragma unroll
      for (int mt = 0; mt < 4; ++mt) {
        #pragma unroll
        for (int reg = 0; reg < 4; ++reg) {
          const float s = acc[mt][nt][reg];
          const bool same = (tir[mt * 4 + reg] == jt);  // j != i guaranteed off-diag
          const float lp = (fminf(s, 1.25f) - 1.25f) * fmaf(s, 64.f, -48.f);
          m = fmaxf(m, same ? lp : -2e30f);
          const float ln = (fmaxf(s, -0.25f) + 0.25f) * fmaf(s, 64.f, -16.f);
          const float en = __expf(ln);
          sn += same ? 0.f : en;
        }
      }
      m = fmaxf(m, __shfl_xor(m, 16));
      m = fmaxf(m, __shfl_xor(m, 32));
      float sp = 0.f;
      #pragma unroll
      for (int mt = 0; mt < 4; ++mt) {
        #pragma unroll
        for (int reg = 0; reg < 4; ++reg) {
          const float s = acc[mt][nt][reg];
          const bool same = (tir[mt * 4 + reg] == jt);
          const float lp = (fminf(s, 1.25f) - 1.25f) * fmaf(s, 64.f, -48.f);
          sp += __expf((same ? lp : -2e30f) - m);
        }
      }
      sp += __shfl_xor(sp, 16); sp += __shfl_xor(sp, 32);
      sn += __shfl_xor(sn, 16); sn += __shfl_xor(sn, 32);
      if (lane < 16) {
        float4 o; o.x = m; o.y = sp; o.z = 0.f; o.w = sn;
        partial[((size_t)jrow * nb + bi) * 2 + (w >> 1)] = o;
      }
    }
  }
}

// ---------------------------------------------------------------------------
// Kernel C: fold 128 partials per row -> row loss. One wave per row.
// ---------------------------------------------------------------------------
__global__ __launch_bounds__(THREADS) void k_reduce(const float4* __restrict__ partial,
                                                    float* __restrict__ row_loss) {
  const int lane = threadIdx.x & 63;
  const int row = blockIdx.x * 4 + (threadIdx.x >> 6);
  const float4 a = partial[(size_t)row * 128 + lane];
  const float4 b = partial[(size_t)row * 128 + 64 + lane];
  float mp = fmaxf(a.x, b.x);
  float sp = a.y * __expf(a.x - mp) + b.y * __expf(b.x - mp);
  float sn = a.w + b.w;
  #pragma unroll
  for (int off = 1; off < 64; off <<= 1) {
    const float m2 = __shfl_xor(mp, off), s2 = __shfl_xor(sp, off);
    const float nm = fmaxf(mp, m2);
    sp = sp * __expf(mp - nm) + s2 * __expf(m2 - nm);
    mp = nm;
    sn += __shfl_xor(sn, off);
  }
  if (lane == 0) {
    float loss = -1.0f;
    if (sp > 0.f && sn > 0.f) {
      const float z = mp + logf(sp) + logf(sn);
      loss = (z > 0.f) ? (z + log1pf(__expf(-z))) : log1pf(__expf(z));
    }
    row_loss[row] = loss;
  }
}

// ---------------------------------------------------------------------------
// Kernel D: masked mean over rows. One block.
// ---------------------------------------------------------------------------
__global__ __launch_bounds__(THREADS) void k_final(const float* __restrict__ row_loss,
                                                   float* __restrict__ out, int B) {
  __shared__ float ssum[4];
  __shared__ float scnt[4];
  const int tid = threadIdx.x;
  float sum = 0.f, cnt = 0.f;
  for (int i = tid; i < B; i += THREADS) {
    const float l = row_loss[i];
    if (l >= 0.f) { sum += l; cnt += 1.f; }
  }
  #pragma unroll
  for (int off = 32; off; off >>= 1) {
    sum += __shfl_xor(sum, off);
    cnt += __shfl_xor(cnt, off);
  }
  if ((tid & 63) == 0) { ssum[tid >> 6] = sum; scnt[tid >> 6] = cnt; }
  __syncthreads();
  if (tid == 0) {
    float ts = 0.f, tc = 0.f;
    #pragma unroll
    for (int w = 0; w < 4; ++w) { ts += ssum[w]; tc += scnt[w]; }
    out[0] = ts / fmaxf(tc, 1.f);
  }
}

// ---------------------------------------------------------------------------
extern "C" void kernel_launch(void* const* d_in, const int* in_sizes, int n_in,
                              void* d_out, int out_size, void* d_ws, size_t ws_size,
                              hipStream_t stream) {
  const float* x = (const float*)d_in[0];
  const int* tgt = (const int*)d_in[1];
  float* out = (float*)d_out;
  const int B = in_sizes[1];
  const int D = in_sizes[0] / B;
  const int nb = B / 128;

  ushortT* xn = (ushortT*)d_ws;                                   // B*D bf16 (16 MB)
  float4* partial = (float4*)((char*)d_ws + (size_t)B * D * 2);   // B*2*nb float4 (16 MB)
  float* row_loss = (float*)((char*)d_ws + (size_t)B * D * 2 + (size_t)B * 2 * nb * 16);

  k_prep<<<B, THREADS, 0, stream>>>(x, xn, D);
  k_main_mfma<<<nb * (nb + 1) / 2, THREADS, 0, stream>>>(xn, tgt, partial, D, nb);
  k_reduce<<<B / 4, THREADS, 0, stream>>>(partial, row_loss);
  k_final<<<1, THREADS, 0, stream>>>(row_loss, out, B);
}

// Round 4
// 248.110 us; speedup vs baseline: 1.0541x; 1.0147x over previous
//
#include <hip/hip_runtime.h>
#include <hip/hip_bf16.h>
#include <math.h>

#define THREADS 256
typedef unsigned short ushortT;
typedef __attribute__((ext_vector_type(8))) short bf16x8;   // 8 bf16 = 4 VGPRs
typedef __attribute__((ext_vector_type(4))) float f32x4;

__device__ __forceinline__ void async16(const ushortT* g, ushortT* l) {
  __builtin_amdgcn_global_load_lds(
      (const __attribute__((address_space(1))) unsigned int*)g,
      (__attribute__((address_space(3))) unsigned int*)l, 16, 0, 0);
}

__device__ __forceinline__ ushortT f2bf(float f) {
  __hip_bfloat16 h = __float2bfloat16(f);
  return *reinterpret_cast<ushortT*>(&h);
}

// ---------------------------------------------------------------------------
// Kernel A: fused L2-norm + bf16 convert. One block per row (256 thr x float4).
// ---------------------------------------------------------------------------
__global__ __launch_bounds__(THREADS) void k_prep(const float* __restrict__ x,
                                                  ushortT* __restrict__ xn, int D) {
  __shared__ float red[4];
  const int row = blockIdx.x;
  const int tid = threadIdx.x;
  const int gid = row * (D / 4) + tid;
  const float4 v = reinterpret_cast<const float4*>(x)[gid];
  float s = v.x * v.x + v.y * v.y + v.z * v.z + v.w * v.w;
  #pragma unroll
  for (int off = 32; off; off >>= 1) s += __shfl_xor(s, off);
  if ((tid & 63) == 0) red[tid >> 6] = s;
  __syncthreads();
  const float tot = red[0] + red[1] + red[2] + red[3];
  const float rn = 1.0f / fmaxf(sqrtf(tot), 1e-12f);
  ushort4 o;
  o.x = f2bf(v.x * rn); o.y = f2bf(v.y * rn);
  o.z = f2bf(v.z * rn); o.w = f2bf(v.w * rn);
  reinterpret_cast<ushort4*>(xn)[gid] = o;
}

// ---------------------------------------------------------------------------
// Kernel B: triangular 128x128 bf16 MFMA tiles + dual-orientation circle-loss
// epilogue. Block b -> (bi <= bj). Grid = nb(nb+1)/2 = 2080 blocks (nb=64).
//
// Round-3 post-mortem: double-buffer + __syncthreads was a no-op (176 us ==
// round-0) because __syncthreads emits s_waitcnt vmcnt(0) -> the prefetch
// issued in the same iteration is drained at that iteration's barrier. The
// pipeline never existed.
//
// This version (T4, counted vmcnt — m218's +38-73% mechanism): raw s_barrier
// + counted s_waitcnt vmcnt(N). Per iter:
//   issue tile kk+1 -> buf[c^1]        (4 loads; 2 on diag)
//   s_waitcnt vmcnt(4|2)               tile kk landed, kk+1 stays IN FLIGHT
//   s_barrier                          (wait own vmcnt THEN barrier: vmcnt is
//                                       per-wave; barrier makes it global)
//   ds_read buf[c] + MFMA              (compiler inserts lgkmcnt)
//   s_barrier                          all reads done before next overwrite
// Hazards: buf[c^1] writes occur only after the previous iteration's post-
// compute barrier (its reads were consumed by MFMAs before that barrier).
// sched_barrier(0) pins ds_reads against hoisting across the raw barrier.
// partial[(row*NB + cb)*2 + half] = {mp, sp, 0, sn}
// ---------------------------------------------------------------------------
__global__ __launch_bounds__(THREADS, 2) void k_main_mfma(const ushortT* __restrict__ xn,
                                                          const int* __restrict__ tgt,
                                                          float4* __restrict__ partial,
                                                          int D, int nb) {
  __shared__ ushortT Asm[2][128 * 32];  // 2 x 8 KB
  __shared__ ushortT Bsm[2][128 * 32];  // 2 x 8 KB

  const int tid = threadIdx.x;
  const int lane = tid & 63;
  const int w = tid >> 6;

  // --- triangular decode: b -> (bi, bj), bi <= bj
  const int b = blockIdx.x;
  int bi = (int)((2.f * nb + 1.f -
                  sqrtf((2.f * nb + 1.f) * (2.f * nb + 1.f) - 8.f * (float)b)) * 0.5f);
  while ((bi + 1) * (2 * nb - bi) / 2 <= b) ++bi;
  while (bi * (2 * nb - bi + 1) / 2 > b) --bi;
  const int bj = bi + (b - bi * (2 * nb - bi + 1) / 2);
  const bool isdiag = (bi == bj);

  const int i0 = bi * 128, j0 = bj * 128;
  const int wr = (w >> 1) * 64, wc = (w & 1) * 64;

  // --- staging: lane fetches (row = lane&15, chunk = lane>>4) of its group
  const int sr = lane & 15, sc = lane >> 4;
  const ushortT* baseA = xn + (size_t)i0 * D;   // wave-uniform 64-bit base
  const ushortT* baseB = xn + (size_t)j0 * D;
  const int offA = (w * 16 + sr) * D + sc * 8;  // 32-bit lane offset
  const int hstep = 64 * D;

  const int aoff = ((w >> 1) * 4) * 512 + lane * 8;   // ushort index
  const int boff = ((w & 1) * 4) * 512 + lane * 8;

  f32x4 acc[4][4];
  #pragma unroll
  for (int mt = 0; mt < 4; ++mt)
    #pragma unroll
    for (int nt = 0; nt < 4; ++nt)
      acc[mt][nt] = (f32x4){0.f, 0.f, 0.f, 0.f};

  const int kiters = D / 32;

  // prologue: stage tile 0 into buffer 0 (loads stay in flight; iter 0 waits)
  async16(baseA + offA, &Asm[0][w * 512]);
  async16(baseA + offA + hstep, &Asm[0][(w + 4) * 512]);
  if (!isdiag) {
    async16(baseB + offA, &Bsm[0][w * 512]);
    async16(baseB + offA + hstep, &Bsm[0][(w + 4) * 512]);
  }

  int cur = 0;
  for (int kk = 0; kk < kiters; ++kk) {
    const bool hasnext = (kk + 1 < kiters);
    if (hasnext) {
      const int ko = (kk + 1) * 32;
      const int nxt = cur ^ 1;
      async16(baseA + offA + ko, &Asm[nxt][w * 512]);
      async16(baseA + offA + hstep + ko, &Asm[nxt][(w + 4) * 512]);
      if (!isdiag) {
        async16(baseB + offA + ko, &Bsm[nxt][w * 512]);
        async16(baseB + offA + hstep + ko, &Bsm[nxt][(w + 4) * 512]);
      }
    }
    // counted wait: only tile kk's loads must have landed; tile kk+1's stay
    // outstanding across the barrier (the whole point).
    if (hasnext) {
      if (isdiag) asm volatile("s_waitcnt vmcnt(2)" ::: "memory");
      else        asm volatile("s_waitcnt vmcnt(4)" ::: "memory");
    } else {
      asm volatile("s_waitcnt vmcnt(0)" ::: "memory");
    }
    __builtin_amdgcn_s_barrier();
    __builtin_amdgcn_sched_barrier(0);

    const ushortT* Ab = Asm[cur];
    const ushortT* Bb = isdiag ? Asm[cur] : Bsm[cur];
    bf16x8 afr[4];
    #pragma unroll
    for (int mt = 0; mt < 4; ++mt)
      afr[mt] = *reinterpret_cast<const bf16x8*>(&Ab[aoff + mt * 512]);
    {
      bf16x8 b0 = *reinterpret_cast<const bf16x8*>(&Bb[boff]);
      bf16x8 b1 = *reinterpret_cast<const bf16x8*>(&Bb[boff + 512]);
      #pragma unroll
      for (int mt = 0; mt < 4; ++mt)
        acc[mt][0] = __builtin_amdgcn_mfma_f32_16x16x32_bf16(afr[mt], b0, acc[mt][0], 0, 0, 0);
      #pragma unroll
      for (int mt = 0; mt < 4; ++mt)
        acc[mt][1] = __builtin_amdgcn_mfma_f32_16x16x32_bf16(afr[mt], b1, acc[mt][1], 0, 0, 0);
      b0 = *reinterpret_cast<const bf16x8*>(&Bb[boff + 2 * 512]);
      b1 = *reinterpret_cast<const bf16x8*>(&Bb[boff + 3 * 512]);
      #pragma unroll
      for (int mt = 0; mt < 4; ++mt)
        acc[mt][2] = __builtin_amdgcn_mfma_f32_16x16x32_bf16(afr[mt], b0, acc[mt][2], 0, 0, 0);
      #pragma unroll
      for (int mt = 0; mt < 4; ++mt)
        acc[mt][3] = __builtin_amdgcn_mfma_f32_16x16x32_bf16(afr[mt], b1, acc[mt][3], 0, 0, 0);
    }
    __builtin_amdgcn_sched_barrier(0);
    __builtin_amdgcn_s_barrier();   // raw: no vmcnt drain — prefetch stays in flight
    cur ^= 1;
  }

  // --- epilogue. C/D layout: col = lane&15, row = (lane>>4)*4 + reg
  const int q = lane >> 4, c = lane & 15;
  int tj[4];
  #pragma unroll
  for (int nt = 0; nt < 4; ++nt) tj[nt] = tgt[j0 + wc + nt * 16 + c];
  int tir[16];
  #pragma unroll
  for (int mt = 0; mt < 4; ++mt) {
    const int4 t4 = *reinterpret_cast<const int4*>(tgt + i0 + wr + mt * 16 + q * 4);
    tir[mt * 4 + 0] = t4.x; tir[mt * 4 + 1] = t4.y;
    tir[mt * 4 + 2] = t4.z; tir[mt * 4 + 3] = t4.w;
  }

  // orientation 1: rows of bi block, cols of bj block
  #pragma unroll
  for (int mt = 0; mt < 4; ++mt) {
    #pragma unroll
    for (int reg = 0; reg < 4; ++reg) {
      const int i = i0 + wr + mt * 16 + q * 4 + reg;
      const int ti = tir[mt * 4 + reg];
      float m = -1e30f, sn = 0.f;
      float sel[4];
      #pragma unroll
      for (int nt = 0; nt < 4; ++nt) {
        const float s = acc[mt][nt][reg];
        const int j = j0 + wc + nt * 16 + c;
        const bool same = (tj[nt] == ti);
        const bool vpos = same && (j != i);
        const float lp = (fminf(s, 1.25f) - 1.25f) * fmaf(s, 64.f, -48.f);
        const float sv = vpos ? lp : -2e30f;
        sel[nt] = sv;
        m = fmaxf(m, sv);
        const float ln = (fmaxf(s, -0.25f) + 0.25f) * fmaf(s, 64.f, -16.f);
        const float en = __expf(ln);
        sn += same ? 0.f : en;
      }
      #pragma unroll
      for (int off = 1; off < 16; off <<= 1) m = fmaxf(m, __shfl_xor(m, off));
      float sp = 0.f;
      #pragma unroll
      for (int nt = 0; nt < 4; ++nt) sp += __expf(sel[nt] - m);
      #pragma unroll
      for (int off = 1; off < 16; off <<= 1) {
        sp += __shfl_xor(sp, off);
        sn += __shfl_xor(sn, off);
      }
      if (c == 0) {
        float4 o; o.x = m; o.y = sp; o.z = 0.f; o.w = sn;
        partial[((size_t)i * nb + bj) * 2 + (w & 1)] = o;
      }
    }
  }

  // orientation 2: rows of bj block, cols of bi block (off-diagonal only).
  // Two-pass, register-lean: pass 1 finds max (sentinel inline) + neg sum,
  // pass 2 recomputes lp and accumulates exp(lp - m).
  if (!isdiag) {
    #pragma unroll
    for (int nt = 0; nt < 4; ++nt) {
      const int jt = tj[nt];
      const int jrow = j0 + wc + nt * 16 + c;
      float m = -1e30f, sn = 0.f;
      #pragma unroll
      for (int mt = 0; mt < 4; ++mt) {
        #pragma unroll
        for (int reg = 0; reg < 4; ++reg) {
          const float s = acc[mt][nt][reg];
          const bool same = (tir[mt * 4 + reg] == jt);  // j != i guaranteed off-diag
          const float lp = (fminf(s, 1.25f) - 1.25f) * fmaf(s, 64.f, -48.f);
          m = fmaxf(m, same ? lp : -2e30f);
          const float ln = (fmaxf(s, -0.25f) + 0.25f) * fmaf(s, 64.f, -16.f);
          const float en = __expf(ln);
          sn += same ? 0.f : en;
        }
      }
      m = fmaxf(m, __shfl_xor(m, 16));
      m = fmaxf(m, __shfl_xor(m, 32));
      float sp = 0.f;
      #pragma unroll
      for (int mt = 0; mt < 4; ++mt) {
        #pragma unroll
        for (int reg = 0; reg < 4; ++reg) {
          const float s = acc[mt][nt][reg];
          const bool same = (tir[mt * 4 + reg] == jt);
          const float lp = (fminf(s, 1.25f) - 1.25f) * fmaf(s, 64.f, -48.f);
          sp += __expf((same ? lp : -2e30f) - m);
        }
      }
      sp += __shfl_xor(sp, 16); sp += __shfl_xor(sp, 32);
      sn += __shfl_xor(sn, 16); sn += __shfl_xor(sn, 32);
      if (lane < 16) {
        float4 o; o.x = m; o.y = sp; o.z = 0.f; o.w = sn;
        partial[((size_t)jrow * nb + bi) * 2 + (w >> 1)] = o;
      }
    }
  }
}

// ---------------------------------------------------------------------------
// Kernel C: fold 128 partials per row -> row loss. One wave per row.
// ---------------------------------------------------------------------------
__global__ __launch_bounds__(THREADS) void k_reduce(const float4* __restrict__ partial,
                                                    float* __restrict__ row_loss) {
  const int lane = threadIdx.x & 63;
  const int row = blockIdx.x * 4 + (threadIdx.x >> 6);
  const float4 a = partial[(size_t)row * 128 + lane];
  const float4 b = partial[(size_t)row * 128 + 64 + lane];
  float mp = fmaxf(a.x, b.x);
  float sp = a.y * __expf(a.x - mp) + b.y * __expf(b.x - mp);
  float sn = a.w + b.w;
  #pragma unroll
  for (int off = 1; off < 64; off <<= 1) {
    const float m2 = __shfl_xor(mp, off), s2 = __shfl_xor(sp, off);
    const float nm = fmaxf(mp, m2);
    sp = sp * __expf(mp - nm) + s2 * __expf(m2 - nm);
    mp = nm;
    sn += __shfl_xor(sn, off);
  }
  if (lane == 0) {
    float loss = -1.0f;
    if (sp > 0.f && sn > 0.f) {
      const float z = mp + logf(sp) + logf(sn);
      loss = (z > 0.f) ? (z + log1pf(__expf(-z))) : log1pf(__expf(z));
    }
    row_loss[row] = loss;
  }
}

// ---------------------------------------------------------------------------
// Kernel D: masked mean over rows. One block.
// ---------------------------------------------------------------------------
__global__ __launch_bounds__(THREADS) void k_final(const float* __restrict__ row_loss,
                                                   float* __restrict__ out, int B) {
  __shared__ float ssum[4];
  __shared__ float scnt[4];
  const int tid = threadIdx.x;
  float sum = 0.f, cnt = 0.f;
  for (int i = tid; i < B; i += THREADS) {
    const float l = row_loss[i];
    if (l >= 0.f) { sum += l; cnt += 1.f; }
  }
  #pragma unroll
  for (int off = 32; off; off >>= 1) {
    sum += __shfl_xor(sum, off);
    cnt += __shfl_xor(cnt, off);
  }
  if ((tid & 63) == 0) { ssum[tid >> 6] = sum; scnt[tid >> 6] = cnt; }
  __syncthreads();
  if (tid == 0) {
    float ts = 0.f, tc = 0.f;
    #pragma unroll
    for (int w = 0; w < 4; ++w) { ts += ssum[w]; tc += scnt[w]; }
    out[0] = ts / fmaxf(tc, 1.f);
  }
}

// ---------------------------------------------------------------------------
extern "C" void kernel_launch(void* const* d_in, const int* in_sizes, int n_in,
                              void* d_out, int out_size, void* d_ws, size_t ws_size,
                              hipStream_t stream) {
  const float* x = (const float*)d_in[0];
  const int* tgt = (const int*)d_in[1];
  float* out = (float*)d_out;
  const int B = in_sizes[1];
  const int D = in_sizes[0] / B;
  const int nb = B / 128;

  ushortT* xn = (ushortT*)d_ws;                                   // B*D bf16 (16 MB)
  float4* partial = (float4*)((char*)d_ws + (size_t)B * D * 2);   // B*2*nb float4 (16 MB)
  float* row_loss = (float*)((char*)d_ws + (size_t)B * D * 2 + (size_t)B * 2 * nb * 16);

  k_prep<<<B, THREADS, 0, stream>>>(x, xn, D);
  k_main_mfma<<<nb * (nb + 1) / 2, THREADS, 0, stream>>>(xn, tgt, partial, D, nb);
  k_reduce<<<B / 4, THREADS, 0, stream>>>(partial, row_loss);
  k_final<<<1, THREADS, 0, stream>>>(row_loss, out, B);
}